// Round 3
// baseline (155.543 us; speedup 1.0000x reference)
//
#include <hip/hip_runtime.h>
#include <math.h>

// Third-order scattering via Parseval:
//   out[b,i,j] = (1/MN^2) * sum_k Fsq_j[k] * Re( XA_{b,i}[k] * conj(X_b[k]) )
// X = fft2(x), XA_i = fft2(abs_eps(ifft2(Fp_i * X))), all in bit-reversed
// (sigma) per-axis frequency layout; filters permuted once to match.
// Only alpha = bandpass (i in 0..31) is needed on the first index.
//
// Two kernels total:
//  k_prep: filter permute + Fsq, and fft2(x) (2 blocks, LDS transpose).
//  k_main: one block per (b,i): full chain in registers + one 64KB LDS tile,
//          j-reduction fused (g never hits global memory).

#define PI_F 3.14159265358979323846f

__device__ __forceinline__ void make_tw(int lane, float* twr, float* twi) {
#pragma unroll
  for (int s = 0; s < 6; ++s) {
    int h = 32 >> s;
    float ang = -PI_F * (float)(lane & (h - 1)) / (float)h;
    float sv, cv;
    sincosf(ang, &sv, &cv);
    twr[s] = cv; twi[s] = sv;
  }
  float ang = -PI_F * (float)lane / 64.0f;
  float sv, cv;
  sincosf(ang, &sv, &cv);
  twr[6] = cv; twi[6] = sv;
}

// Forward DIF: lane t holds a=x[t], b=x[t+64] (natural). Output slot s = X[brev7(s)].
__device__ __forceinline__ void fft128_fwd(float& ar, float& ai, float& br, float& bi,
                                           const float* twr, const float* twi, int lane) {
  float ur = ar + br, ui = ai + bi;
  float vr = ar - br, vi = ai - bi;
  ar = ur; ai = ui;
  br = vr * twr[6] - vi * twi[6];
  bi = vr * twi[6] + vi * twr[6];
#pragma unroll
  for (int s = 0; s < 6; ++s) {
    int h = 32 >> s;
    float wr = twr[s], wi = twi[s];
    bool hi = (lane & h) != 0;
    float pr, pi2;
    pr = __shfl_xor(ar, h, 64); pi2 = __shfl_xor(ai, h, 64);
    if (!hi) { ar += pr; ai += pi2; }
    else { float dr = pr - ar, di = pi2 - ai; ar = dr * wr - di * wi; ai = dr * wi + di * wr; }
    pr = __shfl_xor(br, h, 64); pi2 = __shfl_xor(bi, h, 64);
    if (!hi) { br += pr; bi += pi2; }
    else { float dr = pr - br, di = pi2 - bi; br = dr * wr - di * wi; bi = dr * wi + di * wr; }
  }
}

// Inverse mirror (conjugate twiddles, unnormalized: x128 per axis).
// Input: fwd slot layout. Output: natural (a=y[t], b=y[t+64]).
__device__ __forceinline__ void fft128_inv(float& ar, float& ai, float& br, float& bi,
                                           const float* twr, const float* twi, int lane) {
#pragma unroll
  for (int s = 5; s >= 0; --s) {
    int h = 32 >> s;
    float wr = twr[s], wi = -twi[s];
    bool hi = (lane & h) != 0;
    float pr, pi2;
    pr = __shfl_xor(ar, h, 64); pi2 = __shfl_xor(ai, h, 64);
    if (!hi) { ar += pr * wr - pi2 * wi; ai += pr * wi + pi2 * wr; }
    else { float tr = ar * wr - ai * wi, ti = ar * wi + ai * wr; ar = pr - tr; ai = pi2 - ti; }
    pr = __shfl_xor(br, h, 64); pi2 = __shfl_xor(bi, h, 64);
    if (!hi) { br += pr * wr - pi2 * wi; bi += pr * wi + pi2 * wr; }
    else { float tr = br * wr - bi * wi, ti = br * wi + bi * wr; br = pr - tr; bi = pi2 - ti; }
  }
  float wr = twr[6], wi = -twi[6];
  float tr = br * wr - bi * wi, ti = br * wi + bi * wr;
  float nr = ar + tr, ni = ai + ti;
  br = ar - tr; bi = ai - ti;
  ar = nr; ai = ni;
}

// rows (row r=8w+t, slots c=lane/lane+64) -> cols (col c=8w+ci, slots r=lane/lane+64)
// via 64KB tile in two 64-row chunks; XOR swizzle (c ^ (r&15)) => conflict-free.
__device__ __forceinline__ void transpose_r2c(float (&dr)[16], float (&di)[16],
    float (&er)[8], float (&ei)[8], float (&fr)[8], float (&fi2)[8],
    float2 (*tile)[128], int lane, int w) {
#pragma unroll
  for (int ch = 0; ch < 2; ++ch) {
    if ((w >> 3) == ch) {
#pragma unroll
      for (int t = 0; t < 8; ++t) {
        int r = w * 8 + t;
        int rr = r & 63, sw = r & 15;
        tile[rr][lane ^ sw] = make_float2(dr[2 * t], di[2 * t]);
        tile[rr][(lane + 64) ^ sw] = make_float2(dr[2 * t + 1], di[2 * t + 1]);
      }
    }
    __syncthreads();
    {
      int sw = lane & 15;  // same for lane and lane+64 (64&15==0)
#pragma unroll
      for (int ci = 0; ci < 8; ++ci) {
        int c = w * 8 + ci;
        float2 v = tile[lane][c ^ sw];
        if (ch == 0) { er[ci] = v.x; ei[ci] = v.y; }
        else { fr[ci] = v.x; fi2[ci] = v.y; }
      }
    }
    __syncthreads();
  }
}

// cols -> rows (inverse of transpose_r2c).
__device__ __forceinline__ void transpose_c2r(float (&er)[8], float (&ei)[8],
    float (&fr)[8], float (&fi2)[8], float (&dr)[16], float (&di)[16],
    float2 (*tile)[128], int lane, int w) {
#pragma unroll
  for (int ch = 0; ch < 2; ++ch) {
    {
      int sw = lane & 15;
#pragma unroll
      for (int ci = 0; ci < 8; ++ci) {
        int c = w * 8 + ci;
        float2 v = (ch == 0) ? make_float2(er[ci], ei[ci]) : make_float2(fr[ci], fi2[ci]);
        tile[lane][c ^ sw] = v;
      }
    }
    __syncthreads();
    if ((w >> 3) == ch) {
#pragma unroll
      for (int t = 0; t < 8; ++t) {
        int r = w * 8 + t;
        int rr = r & 63, sw2 = r & 15;
        float2 v0 = tile[rr][lane ^ sw2];
        float2 v1 = tile[rr][(lane + 64) ^ sw2];
        dr[2 * t] = v0.x; di[2 * t] = v0.y;
        dr[2 * t + 1] = v1.x; di[2 * t + 1] = v1.y;
      }
    }
    __syncthreads();
  }
}

// blocks 0..527: permute F -> Fp (sigma layout) and Fsq = Fp^2.
// blocks 528,529: X[b] = fft2(x[b]) in sigma layout, coalesced output.
__global__ __launch_bounds__(1024, 1) void k_prep(const float* __restrict__ x,
    const float* __restrict__ F, float* __restrict__ Fp, float* __restrict__ Fsq,
    float2* __restrict__ X) {
  __shared__ float2 tile[64][128];
  int tid = threadIdx.x;
  if (blockIdx.x < 528) {
    int idx = blockIdx.x * 1024 + tid;  // 33*16384 total
    int c = idx >> 14, su = (idx >> 7) & 127, sv = idx & 127;
    int u = __brev((unsigned)su) >> 25, v = __brev((unsigned)sv) >> 25;
    float f = F[(c << 14) + (u << 7) + v];
    Fp[idx] = f;
    Fsq[idx] = f * f;
    return;
  }
  int b = blockIdx.x - 528;
  int lane = tid & 63, w = tid >> 6;
  float twr[7], twi[7]; make_tw(lane, twr, twi);
  const float* xb = x + b * 16384;
  float dr[16], di[16];
  float er[8], ei[8], fr[8], fi2[8];
#pragma unroll
  for (int t = 0; t < 8; ++t) {  // rows u = 8w+t: fwd v-FFT (real input)
    int r = w * 8 + t;
    float ar = xb[r * 128 + lane], ai2 = 0.f, br = xb[r * 128 + lane + 64], bi = 0.f;
    fft128_fwd(ar, ai2, br, bi, twr, twi, lane);
    dr[2 * t] = ar; di[2 * t] = ai2; dr[2 * t + 1] = br; di[2 * t + 1] = bi;
  }
  transpose_r2c(dr, di, er, ei, fr, fi2, tile, lane, w);
#pragma unroll
  for (int ci = 0; ci < 8; ++ci) {  // cols sv: fwd u-FFT
    float ar = er[ci], ai2 = ei[ci], br = fr[ci], bi = fi2[ci];
    fft128_fwd(ar, ai2, br, bi, twr, twi, lane);
    er[ci] = ar; ei[ci] = ai2; fr[ci] = br; fi2[ci] = bi;
  }
  transpose_c2r(er, ei, fr, fi2, dr, di, tile, lane, w);
#pragma unroll
  for (int t = 0; t < 8; ++t) {  // rows su: coalesced store
    int r = w * 8 + t;
    X[b * 16384 + r * 128 + lane] = make_float2(dr[2 * t], di[2 * t]);
    X[b * 16384 + r * 128 + lane + 64] = make_float2(dr[2 * t + 1], di[2 * t + 1]);
  }
}

// one block per (b, i): i in 0..31 (bandpass only; alpha=32 never used).
__global__ __launch_bounds__(1024, 1) void k_main(const float2* __restrict__ X,
    const float* __restrict__ Fp, const float* __restrict__ Fsq,
    float* __restrict__ out) {
  __shared__ float2 tile[64][128];
  int tid = threadIdx.x;
  int lane = tid & 63, w = tid >> 6;
  int im = blockIdx.x;
  int b = im >> 5, i = im & 31;
  float twr[7], twi[7]; make_tw(lane, twr, twi);
  const float2* Xb = X + b * 16384;
  const float* Fi = Fp + i * 16384;
  float dr[16], di[16];
  float er[8], ei[8], fr[8], fi2[8];

  // P1: rows su = 8w+t: Y = Fp_i * X, inverse v-FFT -> (su, v natural)
#pragma unroll
  for (int t = 0; t < 8; ++t) {
    int r = w * 8 + t;
    float2 x0 = Xb[r * 128 + lane];
    float2 x1 = Xb[r * 128 + lane + 64];
    float f0 = Fi[r * 128 + lane], f1 = Fi[r * 128 + lane + 64];
    float ar = x0.x * f0, ai2 = x0.y * f0, br = x1.x * f1, bi = x1.y * f1;
    fft128_inv(ar, ai2, br, bi, twr, twi, lane);
    dr[2 * t] = ar; di[2 * t] = ai2; dr[2 * t + 1] = br; di[2 * t + 1] = bi;
  }
  transpose_r2c(dr, di, er, ei, fr, fi2, tile, lane, w);

  // P2: per col v=8w+ci: inverse u-FFT, scale+abs_eps, fwd u-FFT (layout-preserving)
  const float sc = 1.0f / 16384.0f;
#pragma unroll
  for (int ci = 0; ci < 8; ++ci) {
    float ar = er[ci], ai2 = ei[ci], br = fr[ci], bi = fi2[ci];
    fft128_inv(ar, ai2, br, bi, twr, twi, lane);
    float t0r = ar * sc, t0i = ai2 * sc, t1r = br * sc, t1i = bi * sc;
    float xa = sqrtf(t0r * t0r + t0i * t0i + 1e-6f);
    float xb2 = sqrtf(t1r * t1r + t1i * t1i + 1e-6f);
    float pr = xa, pi2 = 0.f, qr = xb2, qi = 0.f;
    fft128_fwd(pr, pi2, qr, qi, twr, twi, lane);
    er[ci] = pr; ei[ci] = pi2; fr[ci] = qr; fi2[ci] = qi;
  }
  transpose_c2r(er, ei, fr, fi2, dr, di, tile, lane, w);

  // P3: rows su: fwd v-FFT -> XA (sigma layout); g = Re(XA * conj X)
  float g[16];
#pragma unroll
  for (int t = 0; t < 8; ++t) {
    int r = w * 8 + t;
    float ar = dr[2 * t], ai2 = di[2 * t], br = dr[2 * t + 1], bi = di[2 * t + 1];
    fft128_fwd(ar, ai2, br, bi, twr, twi, lane);
    float2 x0 = Xb[r * 128 + lane], x1 = Xb[r * 128 + lane + 64];
    g[2 * t] = ar * x0.x + ai2 * x0.y;
    g[2 * t + 1] = br * x1.x + bi * x1.y;
  }

  // fused reduce: sums[j] = sum_k g[k] * Fsq_j[k]
  float* sums = (float*)tile;  // tile no longer needed
  if (tid < 33) sums[tid] = 0.f;
  __syncthreads();
  for (int j = 0; j < 33; ++j) {
    const float* Fj = Fsq + j * 16384 + w * 1024;
    float s = 0.f;
#pragma unroll
    for (int t = 0; t < 8; ++t) {
      s += g[2 * t] * Fj[t * 128 + lane];
      s += g[2 * t + 1] * Fj[t * 128 + lane + 64];
    }
#pragma unroll
    for (int off = 32; off > 0; off >>= 1) s += __shfl_xor(s, off, 64);
    if (lane == 0) atomicAdd(&sums[j], s);
  }
  __syncthreads();

  if (tid < 33) {
    int j = tid;
    int j1 = i >> 3, l1 = i & 7;
    const int pref[4] = {0, 264, 464, 600};
    int per = (4 - j1) * 8 + 1;
    int start = pref[j1] + l1 * per;
    int pos = -1;
    if (j == 32) pos = start + per - 1;
    else {
      int j2 = j >> 3;
      if (j2 >= j1) pos = start + (j2 - j1) * 8 + (j & 7);
    }
    if (pos >= 0) out[b * 672 + pos] = sums[j] * (1.0f / 16384.0f) * (1.0f / 16384.0f);
  }
}

extern "C" void kernel_launch(void* const* d_in, const int* in_sizes, int n_in,
                              void* d_out, int out_size, void* d_ws, size_t ws_size,
                              hipStream_t stream) {
  (void)in_sizes; (void)n_in; (void)out_size; (void)ws_size;
  const float* x = (const float*)d_in[0];   // (2,1,128,128)
  const float* F = (const float*)d_in[1];   // (1,33,128,128)
  float* out = (float*)d_out;               // (2,672)
  char* ws = (char*)d_ws;
  // ws: X @0 (262144 B), Fp @262144 (2162688 B), Fsq @2424832 (2162688 B)
  float2* X = (float2*)(ws + 0);
  float* Fp = (float*)(ws + 262144);
  float* Fsq = (float*)(ws + 2424832);

  hipLaunchKernelGGL(k_prep, dim3(530), dim3(1024), 0, stream, x, F, Fp, Fsq, X);
  hipLaunchKernelGGL(k_main, dim3(64), dim3(1024), 0, stream, X, Fp, Fsq, out);
}

// Round 4
// 123.355 us; speedup vs baseline: 1.2609x; 1.2609x over previous
//
#include <hip/hip_runtime.h>
#include <math.h>

// Third-order scattering via double-Parseval:
//   out[b,i,j] = (1/MN^2) * sum_n xa_{b,i}[n] * d_{b,j}[n]
// with xa_i = abs_eps(ifft2(Fp_i * X)), d_j = Re(inv2_un(Fsq_j * X)),
// X = fft2(x); all frequency-domain arrays in bit-reversed (sigma) per-axis
// layout (filters permuted once); spatial arrays in col-major (v,u) layout.
//
// 3 dispatches:
//  k_prep   : permute F -> Fp, Fsq=Fp^2 (528 blks) + fft2(x) -> X (2 fat blks)
//  k_fields : 130 fat blocks: 66 -> d fields, 64 -> xa fields (same code path)
//  k_dot    : 1344 blocks: out[pos] = dot(xa_row, d_row) / MN^2

#define PI_F 3.14159265358979323846f

__device__ __forceinline__ void make_tw(int lane, float* twr, float* twi) {
#pragma unroll
  for (int s = 0; s < 6; ++s) {
    int h = 32 >> s;
    float ang = -PI_F * (float)(lane & (h - 1)) / (float)h;
    float sv, cv;
    sincosf(ang, &sv, &cv);
    twr[s] = cv; twi[s] = sv;
  }
  float ang = -PI_F * (float)lane / 64.0f;
  float sv, cv;
  sincosf(ang, &sv, &cv);
  twr[6] = cv; twi[6] = sv;
}

// Forward DIF: lane t holds a=x[t], b=x[t+64] (natural). Output slot s = X[brev7(s)].
__device__ __forceinline__ void fft128_fwd(float& ar, float& ai, float& br, float& bi,
                                           const float* twr, const float* twi, int lane) {
  float ur = ar + br, ui = ai + bi;
  float vr = ar - br, vi = ai - bi;
  ar = ur; ai = ui;
  br = vr * twr[6] - vi * twi[6];
  bi = vr * twi[6] + vi * twr[6];
#pragma unroll
  for (int s = 0; s < 6; ++s) {
    int h = 32 >> s;
    float wr = twr[s], wi = twi[s];
    bool hi = (lane & h) != 0;
    float pr, pi2;
    pr = __shfl_xor(ar, h, 64); pi2 = __shfl_xor(ai, h, 64);
    if (!hi) { ar += pr; ai += pi2; }
    else { float dr = pr - ar, di = pi2 - ai; ar = dr * wr - di * wi; ai = dr * wi + di * wr; }
    pr = __shfl_xor(br, h, 64); pi2 = __shfl_xor(bi, h, 64);
    if (!hi) { br += pr; bi += pi2; }
    else { float dr = pr - br, di = pi2 - bi; br = dr * wr - di * wi; bi = dr * wi + di * wr; }
  }
}

// Inverse mirror (conjugate twiddles, unnormalized: x128 per axis).
// Input: fwd slot layout. Output: natural (a=y[t], b=y[t+64]).
__device__ __forceinline__ void fft128_inv(float& ar, float& ai, float& br, float& bi,
                                           const float* twr, const float* twi, int lane) {
#pragma unroll
  for (int s = 5; s >= 0; --s) {
    int h = 32 >> s;
    float wr = twr[s], wi = -twi[s];
    bool hi = (lane & h) != 0;
    float pr, pi2;
    pr = __shfl_xor(ar, h, 64); pi2 = __shfl_xor(ai, h, 64);
    if (!hi) { ar += pr * wr - pi2 * wi; ai += pr * wi + pi2 * wr; }
    else { float tr = ar * wr - ai * wi, ti = ar * wi + ai * wr; ar = pr - tr; ai = pi2 - ti; }
    pr = __shfl_xor(br, h, 64); pi2 = __shfl_xor(bi, h, 64);
    if (!hi) { br += pr * wr - pi2 * wi; bi += pr * wi + pi2 * wr; }
    else { float tr = br * wr - bi * wi, ti = br * wi + bi * wr; br = pr - tr; bi = pi2 - ti; }
  }
  float wr = twr[6], wi = -twi[6];
  float tr = br * wr - bi * wi, ti = br * wi + bi * wr;
  float nr = ar + tr, ni = ai + ti;
  br = ar - tr; bi = ai - ti;
  ar = nr; ai = ni;
}

// rows (row r=8w+t, slots c=lane/lane+64) -> cols (col c=8w+ci, slots r=lane/lane+64)
// via 64KB tile in two 64-row chunks; XOR swizzle (c ^ (r&15)) => conflict-free.
__device__ __forceinline__ void transpose_r2c(float (&dr)[16], float (&di)[16],
    float (&er)[8], float (&ei)[8], float (&fr)[8], float (&fi2)[8],
    float2 (*tile)[128], int lane, int w) {
#pragma unroll
  for (int ch = 0; ch < 2; ++ch) {
    if ((w >> 3) == ch) {
#pragma unroll
      for (int t = 0; t < 8; ++t) {
        int r = w * 8 + t;
        int rr = r & 63, sw = r & 15;
        tile[rr][lane ^ sw] = make_float2(dr[2 * t], di[2 * t]);
        tile[rr][(lane + 64) ^ sw] = make_float2(dr[2 * t + 1], di[2 * t + 1]);
      }
    }
    __syncthreads();
    {
      int sw = lane & 15;
#pragma unroll
      for (int ci = 0; ci < 8; ++ci) {
        int c = w * 8 + ci;
        float2 v = tile[lane][c ^ sw];
        if (ch == 0) { er[ci] = v.x; ei[ci] = v.y; }
        else { fr[ci] = v.x; fi2[ci] = v.y; }
      }
    }
    __syncthreads();
  }
}

// cols -> rows (inverse of transpose_r2c). (used by k_prep only)
__device__ __forceinline__ void transpose_c2r(float (&er)[8], float (&ei)[8],
    float (&fr)[8], float (&fi2)[8], float (&dr)[16], float (&di)[16],
    float2 (*tile)[128], int lane, int w) {
#pragma unroll
  for (int ch = 0; ch < 2; ++ch) {
    {
      int sw = lane & 15;
#pragma unroll
      for (int ci = 0; ci < 8; ++ci) {
        int c = w * 8 + ci;
        float2 v = (ch == 0) ? make_float2(er[ci], ei[ci]) : make_float2(fr[ci], fi2[ci]);
        tile[lane][c ^ sw] = v;
      }
    }
    __syncthreads();
    if ((w >> 3) == ch) {
#pragma unroll
      for (int t = 0; t < 8; ++t) {
        int r = w * 8 + t;
        int rr = r & 63, sw2 = r & 15;
        float2 v0 = tile[rr][lane ^ sw2];
        float2 v1 = tile[rr][(lane + 64) ^ sw2];
        dr[2 * t] = v0.x; di[2 * t] = v0.y;
        dr[2 * t + 1] = v1.x; di[2 * t + 1] = v1.y;
      }
    }
    __syncthreads();
  }
}

// blocks 0..527: permute F -> Fp (sigma layout) and Fsq = Fp^2.
// blocks 528,529: X[b] = fft2(x[b]) in sigma layout.
__global__ __launch_bounds__(1024, 4) void k_prep(const float* __restrict__ x,
    const float* __restrict__ F, float* __restrict__ Fp, float* __restrict__ Fsq,
    float2* __restrict__ X) {
  __shared__ float2 tile[64][128];
  int tid = threadIdx.x;
  if (blockIdx.x < 528) {
    int idx = blockIdx.x * 1024 + tid;  // 33*16384 total
    int c = idx >> 14, su = (idx >> 7) & 127, sv = idx & 127;
    int u = __brev((unsigned)su) >> 25, v = __brev((unsigned)sv) >> 25;
    float f = F[(c << 14) + (u << 7) + v];
    Fp[idx] = f;
    Fsq[idx] = f * f;
    return;
  }
  int b = blockIdx.x - 528;
  int lane = tid & 63, w = tid >> 6;
  float twr[7], twi[7]; make_tw(lane, twr, twi);
  const float* xb = x + b * 16384;
  float dr[16], di[16];
  float er[8], ei[8], fr[8], fi2[8];
#pragma unroll
  for (int t = 0; t < 8; ++t) {  // rows u = 8w+t: fwd v-FFT (real input)
    int r = w * 8 + t;
    float ar = xb[r * 128 + lane], ai2 = 0.f, br = xb[r * 128 + lane + 64], bi = 0.f;
    fft128_fwd(ar, ai2, br, bi, twr, twi, lane);
    dr[2 * t] = ar; di[2 * t] = ai2; dr[2 * t + 1] = br; di[2 * t + 1] = bi;
  }
  transpose_r2c(dr, di, er, ei, fr, fi2, tile, lane, w);
#pragma unroll
  for (int ci = 0; ci < 8; ++ci) {  // cols sv: fwd u-FFT
    float ar = er[ci], ai2 = ei[ci], br = fr[ci], bi = fi2[ci];
    fft128_fwd(ar, ai2, br, bi, twr, twi, lane);
    er[ci] = ar; ei[ci] = ai2; fr[ci] = br; fi2[ci] = bi;
  }
  transpose_c2r(er, ei, fr, fi2, dr, di, tile, lane, w);
#pragma unroll
  for (int t = 0; t < 8; ++t) {  // rows su: coalesced store
    int r = w * 8 + t;
    X[b * 16384 + r * 128 + lane] = make_float2(dr[2 * t], di[2 * t]);
    X[b * 16384 + r * 128 + lane + 64] = make_float2(dr[2 * t + 1], di[2 * t + 1]);
  }
}

// blocks 0..65:  (b,j): d  = Re(inv2_un(Fsq_j * X_b))           -> dfld[b*33+j]
// blocks 66..129:(b,i): xa = abs_eps(inv2_un(Fp_i * X_b)/MN)    -> xa[b*32+i]
// Both stored col-major: arr[im][c*128 + u], c = column (v), u = row.
__global__ __launch_bounds__(1024, 4) void k_fields(const float2* __restrict__ X,
    const float* __restrict__ Fp, const float* __restrict__ Fsq,
    float* __restrict__ dfld, float* __restrict__ xa) {
  __shared__ float2 tile[64][128];
  int tid = threadIdx.x, lane = tid & 63, w = tid >> 6;
  bool isd = (blockIdx.x < 66);
  int b, f;
  const float* Fb;
  float* optr;
  if (isd) {
    b = blockIdx.x / 33; f = blockIdx.x - b * 33;
    Fb = Fsq + f * 16384; optr = dfld + blockIdx.x * 16384;
  } else {
    int q = blockIdx.x - 66; b = q >> 5; f = q & 31;
    Fb = Fp + f * 16384; optr = xa + q * 16384;
  }
  float twr[7], twi[7]; make_tw(lane, twr, twi);
  const float2* Xb = X + b * 16384;
  float dr[16], di[16];
  float er[8], ei[8], fr[8], fi2[8];

  // P1: rows su = 8w+t: Y = Fb * X, inverse v-FFT -> (su, v natural)
#pragma unroll
  for (int t = 0; t < 8; ++t) {
    int r = w * 8 + t;
    float2 x0 = Xb[r * 128 + lane];
    float2 x1 = Xb[r * 128 + lane + 64];
    float f0 = Fb[r * 128 + lane], f1 = Fb[r * 128 + lane + 64];
    float ar = x0.x * f0, ai2 = x0.y * f0, br = x1.x * f1, bi = x1.y * f1;
    fft128_inv(ar, ai2, br, bi, twr, twi, lane);
    dr[2 * t] = ar; di[2 * t] = ai2; dr[2 * t + 1] = br; di[2 * t + 1] = bi;
  }
  transpose_r2c(dr, di, er, ei, fr, fi2, tile, lane, w);

  // P2: per col v=8w+ci: inverse u-FFT, then store Re (d) or abs_eps (xa).
  const float sc = 1.0f / 16384.0f;
#pragma unroll
  for (int ci = 0; ci < 8; ++ci) {
    int c = w * 8 + ci;
    float ar = er[ci], ai2 = ei[ci], br = fr[ci], bi = fi2[ci];
    fft128_inv(ar, ai2, br, bi, twr, twi, lane);
    if (isd) {
      optr[c * 128 + lane] = ar;
      optr[c * 128 + lane + 64] = br;
    } else {
      float t0r = ar * sc, t0i = ai2 * sc, t1r = br * sc, t1i = bi * sc;
      optr[c * 128 + lane] = sqrtf(t0r * t0r + t0i * t0i + 1e-6f);
      optr[c * 128 + lane + 64] = sqrtf(t1r * t1r + t1i * t1i + 1e-6f);
    }
  }
}

// out[b*672+t]: decode (i,j) from t, dot(xa[b*32+i], d[b*33+j]) * (1/MN^2).
__global__ __launch_bounds__(256) void k_dot(const float* __restrict__ xa,
    const float* __restrict__ dfld, float* __restrict__ out) {
  int o = blockIdx.x;  // 0..1343
  int b = o / 672, t = o - b * 672;
  int rem = t, j1 = 0;
  for (;;) {
    int c = 8 * ((4 - j1) * 8 + 1);
    if (rem < c) break;
    rem -= c; ++j1;
  }
  int per = (4 - j1) * 8 + 1;
  int l1 = rem / per, rr = rem - l1 * per;
  int i = j1 * 8 + l1;
  int j = (rr == per - 1) ? 32 : (j1 * 8 + rr);
  const float4* A = (const float4*)(xa + (b * 32 + i) * 16384);
  const float4* B = (const float4*)(dfld + (b * 33 + j) * 16384);
  float s = 0.f;
#pragma unroll 4
  for (int k = threadIdx.x; k < 4096; k += 256) {
    float4 a = A[k], bb = B[k];
    s += a.x * bb.x + a.y * bb.y + a.z * bb.z + a.w * bb.w;
  }
#pragma unroll
  for (int off = 32; off > 0; off >>= 1) s += __shfl_xor(s, off, 64);
  __shared__ float red[4];
  if ((threadIdx.x & 63) == 0) red[threadIdx.x >> 6] = s;
  __syncthreads();
  if (threadIdx.x == 0) {
    float tot = (red[0] + red[1]) + (red[2] + red[3]);
    out[o] = tot * (1.0f / 16384.0f) * (1.0f / 16384.0f);
  }
}

extern "C" void kernel_launch(void* const* d_in, const int* in_sizes, int n_in,
                              void* d_out, int out_size, void* d_ws, size_t ws_size,
                              hipStream_t stream) {
  (void)in_sizes; (void)n_in; (void)out_size; (void)ws_size;
  const float* x = (const float*)d_in[0];   // (2,1,128,128)
  const float* F = (const float*)d_in[1];   // (1,33,128,128)
  float* out = (float*)d_out;               // (2,672)
  char* ws = (char*)d_ws;
  // ws: X @0 (262144 B) | Fp @262144 (2162688 B) | Fsq @2424832 (2162688 B)
  //   | dfld @4587520 (66*16384*4 = 4325376 B) | xa @8912896 (64*16384*4 = 4194304 B)
  float2* X = (float2*)(ws + 0);
  float* Fp = (float*)(ws + 262144);
  float* Fsq = (float*)(ws + 2424832);
  float* dfld = (float*)(ws + 4587520);
  float* xa = (float*)(ws + 8912896);

  hipLaunchKernelGGL(k_prep, dim3(530), dim3(1024), 0, stream, x, F, Fp, Fsq, X);
  hipLaunchKernelGGL(k_fields, dim3(130), dim3(1024), 0, stream, X, Fp, Fsq, dfld, xa);
  hipLaunchKernelGGL(k_dot, dim3(1344), dim3(256), 0, stream, xa, dfld, out);
}